// Round 1
// baseline (187.973 us; speedup 1.0000x reference)
//
#include <hip/hip_runtime.h>
#include <hip/hip_bf16.h>
#include <math.h>

// Problem constants
#define B_    8
#define T_    2048
#define NTOK  (B_ * T_)   // 16384 tokens
#define D_    512
#define E_    8
#define NPAIR 28          // unordered expert pairs (top-2 always distinct)
#define CAP   NTOK        // per-pair bucket capacity (worst case)

// worklist: wl[0] = total mtiles; wl[1+i] = (pair<<8)|mtile.
// Sum ceil(cnt_p/128) <= 128 + 27 = 155 -> pad to 160 (multiple of 8 for XCD map)
#define WL_MAX 160

// router v6: 1024 blocks x 256 thr; 16 tok/block, 4 tok/wave.
#define RV_TOK    16
#define RV_THR    256
#define XS_STRIDE 132
#define WS_FLOATS 2108

typedef __attribute__((ext_vector_type(4))) float f32x4;
typedef __attribute__((ext_vector_type(8))) short short8;  // 8 bf16 (MFMA a/b frag)

__device__ __forceinline__ void async_load16(const void* g, void* l) {
    __builtin_amdgcn_global_load_lds(
        (const __attribute__((address_space(1))) unsigned int*)g,
        (__attribute__((address_space(3))) unsigned int*)l,
        16, 0, 0);
}

// ---------------------------------------------------------------------------
// Kernel 1: Wk[e][d][h] fp32 -> Wkt[e][h][d] bf16 (B^T layout for GEMM).
// ---------------------------------------------------------------------------
__global__ __launch_bounds__(256) void transpose_wk(
    const float* __restrict__ Wk, __hip_bfloat16* __restrict__ Wkt)
{
    __shared__ float tile[32][33];
    const int e  = blockIdx.z;
    const int d0 = blockIdx.x * 32;
    const int h0 = blockIdx.y * 32;
    const int tx = threadIdx.x, ty = threadIdx.y;

    const float* src = Wk + ((size_t)e * D_ + d0) * D_ + h0;
    #pragma unroll
    for (int r = ty; r < 32; r += 8)
        tile[r][tx] = src[(size_t)r * D_ + tx];
    __syncthreads();
    __hip_bfloat16* dst = Wkt + ((size_t)e * D_ + h0) * D_ + d0;
    #pragma unroll
    for (int r = ty; r < 32; r += 8)
        dst[(size_t)r * D_ + tx] = __float2bfloat16(tile[tx][r]);
}

// ---------------------------------------------------------------------------
// Kernel 2: router v6 (unchanged). x staged+bf16-converted once, W staged per
// 128-k chunk, fp32 fma, k-split lanes; 1024 blocks.
// ---------------------------------------------------------------------------
__global__ __launch_bounds__(RV_THR) void router_kernel(
    const float* __restrict__ x,     // [NTOK][D]
    const float* __restrict__ eps,   // [NTOK][E]
    const float* __restrict__ Wr,    // [D][E]
    const float* __restrict__ br,    // [E]
    const float* __restrict__ Wn,    // [D][E]
    const float* __restrict__ bn,    // [E]
    __hip_bfloat16* __restrict__ xb, // out: [NTOK][D] bf16
    uint4* __restrict__ top2)        // out: [NTOK] {i1|i2<<8, g1bits, g2bits}
{
    __shared__ float xs[RV_TOK * XS_STRIDE];  // 8.4 KB
    __shared__ float wsh[WS_FLOATS];          // 8.4 KB; row k at k*16+(k>>3)*4

    const int tid  = threadIdx.x;
    const int tok0 = blockIdx.x * RV_TOK;
    const int lane = tid & 63, wv = tid >> 6;
    const int kidx = lane >> 2, ts = lane & 3;
    const int tl = wv * 4 + ts;                // this lane's token
    const int wk = tid >> 1, wh = tid & 1;     // W stager: row, half

    float acc[16];  // [0..7]=x.Wr per expert, [8..15]=x.Wn
    #pragma unroll
    for (int c = 0; c < 16; ++c) acc[c] = 0.f;

    for (int kc = 0; kc < D_; kc += 128) {
        // stage x chunk [16 tok][128 k] + fused bf16 convert/store
        #pragma unroll
        for (int it = 0; it < 2; ++it) {
            const int f   = it * RV_THR + tid;      // f32x4 index in [0,512)
            const int row = f >> 5, col = (f & 31) * 4;
            const f32x4 v = *(const f32x4*)(x + (size_t)(tok0 + row) * D_ + kc + col);
            *(f32x4*)(xs + row * XS_STRIDE + col) = v;
            union { __hip_bfloat16 h[4]; uint2 u; } cv;
            cv.h[0] = __float2bfloat16(v.x); cv.h[1] = __float2bfloat16(v.y);
            cv.h[2] = __float2bfloat16(v.z); cv.h[3] = __float2bfloat16(v.w);
            *(uint2*)(xb + (size_t)(tok0 + row) * D_ + kc + col) = cv.u;
        }
        // stage W chunk [128 k][16 c] skewed; cols 0-7 = Wr, 8-15 = Wn
        {
            const float* src = (wh ? Wn : Wr) + (size_t)(kc + wk) * E_;
            const f32x4 w0 = *(const f32x4*)(src);
            const f32x4 w1 = *(const f32x4*)(src + 4);
            float* dst = wsh + wk * 16 + (wk >> 3) * 4 + wh * 8;
            *(f32x4*)(dst)     = w0;
            *(f32x4*)(dst + 4) = w1;
        }
        __syncthreads();

        // compute: this lane's 8 k-values of the chunk (k = kidx*8 + kk)
        const float* xra = xs + tl * XS_STRIDE + kidx * 8;
        const f32x4 xa0 = *(const f32x4*)(xra);
        const f32x4 xa1 = *(const f32x4*)(xra + 4);
        const float* wbase = wsh + kidx * 132;  // (kidx*8)*16 + kidx*4
        #pragma unroll
        for (int kk = 0; kk < 8; ++kk) {
            const float xav = (kk < 4) ? xa0[kk] : xa1[kk - 4];
            const float* wrow = wbase + kk * 16;
            #pragma unroll
            for (int c4 = 0; c4 < 4; ++c4) {
                const f32x4 w = *(const f32x4*)(wrow + c4 * 4);
                #pragma unroll
                for (int c = 0; c < 4; ++c)
                    acc[c4 * 4 + c] = fmaf(xav, w[c], acc[c4 * 4 + c]);
            }
        }
        __syncthreads();
    }

    // reduce across the 16 kidx lanes (stride 4): xor 4,8,16,32
    #pragma unroll
    for (int off = 4; off < 64; off <<= 1) {
        #pragma unroll
        for (int c = 0; c < 16; ++c)
            acc[c] += __shfl_xor(acc[c], off);
    }

    if (lane < 4) {  // kidx==0 lanes hold full dots for token tl
        const int tok = tok0 + tl;
        float nv[8];
        #pragma unroll
        for (int e = 0; e < 8; ++e) {
            const float nl = acc[8 + e] + bn[e];
            // jax.nn.softplus = max(z,0) + log1p(exp(-|z|))
            const float sp = fmaxf(nl, 0.f) + log1pf(expf(-fabsf(nl)));
            nv[e] = acc[e] + br[e] + eps[(size_t)tok * E_ + e] * sp;
        }
        // top-2, lax.top_k tie semantics (lowest index wins ties)
        int i1 = 0; float v1 = nv[0];
        #pragma unroll
        for (int e = 1; e < 8; ++e)
            if (nv[e] > v1) { v1 = nv[e]; i1 = e; }
        int i2 = -1; float v2 = -3.4e38f;
        #pragma unroll
        for (int e = 0; e < 8; ++e)
            if (e != i1 && nv[e] > v2) { v2 = nv[e]; i2 = e; }
        const float t  = expf(v2 - v1);
        const float g1 = 1.f / (1.f + t);
        const float g2 = t / (1.f + t);
        top2[tok] = make_uint4((unsigned)i1 | ((unsigned)i2 << 8),
                               __float_as_uint(g1), __float_as_uint(g2), 0u);
    }
}

// ---------------------------------------------------------------------------
// Kernel 3: PAIR bucket build (unchanged). Token -> one of 28 expert-pair
// buckets. LDS histogram -> 28 global atomics per block.
// ---------------------------------------------------------------------------
__global__ __launch_bounds__(256) void bucket_kernel(
    const uint4* __restrict__ top2,
    int* __restrict__ counts,     // [NPAIR] pre-zeroed
    uint4* __restrict__ entries)  // [NPAIR][CAP]
{
    __shared__ int hist[NPAIR];
    __shared__ int base[NPAIR];
    const int tid = threadIdx.x;
    const int tok = blockIdx.x * 256 + tid;
    if (tid < NPAIR) hist[tid] = 0;
    __syncthreads();
    const uint4 t = top2[tok];
    const int i1 = t.x & 0xff, i2 = (t.x >> 8) & 0xff;
    const int a = min(i1, i2), b = max(i1, i2);
    const unsigned ga = (i1 < i2) ? t.y : t.z;   // gate of expert a
    const unsigned gb = (i1 < i2) ? t.z : t.y;   // gate of expert b
    const int p = a * (15 - a) / 2 + (b - a - 1);
    const int l = atomicAdd(&hist[p], 1);
    __syncthreads();
    if (tid < NPAIR) base[tid] = atomicAdd(counts + tid, hist[tid]);
    __syncthreads();
    entries[(size_t)p * CAP + base[p] + l] = make_uint4((unsigned)tok, ga, gb, 0u);
}

// ---------------------------------------------------------------------------
// Kernel 3b: build worklist from final counts. 1 block, 1 wave.
// wl[0] = nm_total (<= 155); wl[1+i] = (p<<8)|mt.
// ---------------------------------------------------------------------------
__global__ __launch_bounds__(64) void build_wl(
    const int* __restrict__ counts, int* __restrict__ wl)
{
    const int t = threadIdx.x;  // 0..63, single wave
    const int nm = (t < NPAIR) ? ((counts[t] + 127) >> 7) : 0;
    int inc = nm;  // inclusive prefix sum across the wave
    #pragma unroll
    for (int d = 1; d < 64; d <<= 1) {
        const int v = __shfl_up(inc, d);
        if (t >= d) inc += v;
    }
    if (t == 63) wl[0] = inc;           // total mtiles
    const int ex = inc - nm;            // exclusive prefix
    for (int m = 0; m < nm; ++m)
        wl[1 + ex + m] = (t << 8) | m;
}

// ---------------------------------------------------------------------------
// Kernel 4: pair-grouped expert GEMM, DIRECT output.
//   R7 changes vs R6:
//   * worklist-driven compact grid (640 blocks, all-resident, no empty churn)
//     with XCD-aware id decode: the 4 n-tiles sharing one A-panel map to the
//     same XCD (id%8 == mtile%8) and are dispatch-adjacent -> A reuse in L2.
//   * k-major 16B-chunk LDS layout [kc(4)][row(128)]: linear global_load_lds
//     dest, per-lane global source remapped (rule: swizzle-by-source). Each
//     16-lane ds_read_b128 phase reads 256B contiguous -> zero bank conflicts
//     (was ~8-way on the [row][32] layout; 1.72M conflict cycles).
//   * double-buffered, ONE barrier per K-step (T3-minimum): stage next tile
//     before computing current; __syncthreads drains vmcnt+lgkm once.
// ---------------------------------------------------------------------------
__global__ __launch_bounds__(256, 2) void moe_gemm(
    const __hip_bfloat16* __restrict__ xb,   // [NTOK][D] bf16
    const __hip_bfloat16* __restrict__ wkt,  // [E][D(out)][D(in)] bf16 (B^T)
    const float* __restrict__ bk,            // [E][D]
    const int* __restrict__ counts,          // [NPAIR]
    const uint4* __restrict__ entries,       // [NPAIR][CAP]
    const int* __restrict__ wl,              // [1+WL_MAX]
    float* __restrict__ out)                 // [NTOK][D] fp32 (fully written)
{
    constexpr int BM = 128, BN = 128, BK = 32;
    // k-major chunk layout: elem offset = kc*1024 + row*8 + j  (kc=k/8 in BK)
    __shared__ __hip_bfloat16 As[2][BM * BK];         // 2 x 8 KB
    __shared__ __hip_bfloat16 Bs[2][2][BN * BK];      // 2 x 16 KB
    __shared__ uint4 ent[BM];                         // 2 KB   (total 50 KB)

    // id = g*32 + nt*8 + j ; mtile = g*8 + j ; XCD = id%8 = j for all 4 nt
    const int id = blockIdx.x;
    const int g = id >> 5, r = id & 31;
    const int nt = r >> 3;
    const int mi = g * 8 + (r & 7);
    const int nmtot = wl[0];
    if (mi >= nmtot) return;
    const int we = wl[1 + mi];
    const int p = we >> 8, mt = we & 255;
    const int cnt = counts[p];

    // decode pair p -> (e1 < e2)
    int e1 = 0, rem = p;
    while (rem >= 7 - e1) { rem -= 7 - e1; ++e1; }
    const int e2 = e1 + 1 + rem;

    const int tid = threadIdx.x;
    const int wave = tid >> 6, lane = tid & 63;

    if (tid < BM) {
        const int idx = mt * BM + tid;
        ent[tid] = (idx < cnt) ? entries[(size_t)p * CAP + idx]
                               : make_uint4(0u, 0u, 0u, 0u);
    }
    __syncthreads();

    const int quad = lane >> 4, lr = lane & 15;
    const int wm = wave >> 1, wn = wave & 1;

    // per-lane global sources for k-major staging: wave w stages kc=w
    // (k offset w*8) for all 128 rows (2 calls of 64 rows each).
    const size_t tokLo = ent[lane].x;
    const size_t tokHi = ent[64 + lane].x;
    const __hip_bfloat16* gA0 = xb + tokLo * D_ + wave * 8;
    const __hip_bfloat16* gA1 = xb + tokHi * D_ + wave * 8;
    const __hip_bfloat16* gB1 = wkt + ((size_t)(e1 * D_ + nt * BN) + lane) * D_ + wave * 8;
    const __hip_bfloat16* gB2 = wkt + ((size_t)(e2 * D_ + nt * BN) + lane) * D_ + wave * 8;

    f32x4 accA[4][4], accB[4][4];
    #pragma unroll
    for (int i = 0; i < 4; ++i)
        #pragma unroll
        for (int j = 0; j < 4; ++j) {
            accA[i][j] = (f32x4){0.f, 0.f, 0.f, 0.f};
            accB[i][j] = (f32x4){0.f, 0.f, 0.f, 0.f};
        }

#define STAGE(buf, k0) do {                                        \
        __hip_bfloat16* aB  = &As[buf][wave * 1024];               \
        __hip_bfloat16* b1B = &Bs[buf][0][wave * 1024];            \
        __hip_bfloat16* b2B = &Bs[buf][1][wave * 1024];            \
        async_load16(gA0 + (k0), aB);                              \
        async_load16(gA1 + (k0), aB + 512);                        \
        async_load16(gB1 + (k0), b1B);                             \
        async_load16(gB1 + 64 * D_ + (k0), b1B + 512);             \
        async_load16(gB2 + (k0), b2B);                             \
        async_load16(gB2 + 64 * D_ + (k0), b2B + 512);             \
    } while (0)

#define COMPUTE(buf) do {                                                      \
        const __hip_bfloat16* aP  = &As[buf][quad * 1024 + lr * 8];            \
        const __hip_bfloat16* b1P = &Bs[buf][0][quad * 1024 + lr * 8];         \
        const __hip_bfloat16* b2P = &Bs[buf][1][quad * 1024 + lr * 8];         \
        short8 a[4], b1[4], b2[4];                                             \
        _Pragma("unroll")                                                      \
        for (int i = 0; i < 4; ++i)                                            \
            a[i] = *(const short8*)(aP + (wm * 64 + i * 16) * 8);              \
        _Pragma("unroll")                                                      \
        for (int j = 0; j < 4; ++j) {                                          \
            b1[j] = *(const short8*)(b1P + (wn * 64 + j * 16) * 8);            \
            b2[j] = *(const short8*)(b2P + (wn * 64 + j * 16) * 8);            \
        }                                                                      \
        _Pragma("unroll")                                                      \
        for (int i = 0; i < 4; ++i)                                            \
            _Pragma("unroll")                                                  \
            for (int j = 0; j < 4; ++j) {                                      \
                accA[i][j] = __builtin_amdgcn_mfma_f32_16x16x32_bf16(          \
                    a[i], b1[j], accA[i][j], 0, 0, 0);                         \
                accB[i][j] = __builtin_amdgcn_mfma_f32_16x16x32_bf16(          \
                    a[i], b2[j], accB[i][j], 0, 0, 0);                         \
            }                                                                  \
    } while (0)

    STAGE(0, 0);
    __syncthreads();          // vmcnt(0): buf0 ready

    int cur = 0;
    for (int k0 = BK; k0 < D_; k0 += BK) {
        STAGE(cur ^ 1, k0);   // issue next tile's loads (latency hides below)
        COMPUTE(cur);
        __syncthreads();      // single drain/barrier per K-step
        cur ^= 1;
    }
    COMPUTE(cur);             // last tile

#undef STAGE
#undef COMPUTE

    const int colbase = nt * BN + wn * 64 + lr;
    float bkA[4], bkB[4];
    #pragma unroll
    for (int j = 0; j < 4; ++j) {
        bkA[j] = bk[e1 * D_ + colbase + j * 16];
        bkB[j] = bk[e2 * D_ + colbase + j * 16];
    }

    #pragma unroll
    for (int i = 0; i < 4; ++i) {
        #pragma unroll
        for (int rr = 0; rr < 4; ++rr) {
            const int row = wm * 64 + i * 16 + quad * 4 + rr;  // C: row = quad*4+reg
            if (mt * BM + row < cnt) {
                const uint4 en = ent[row];
                const float ga = __uint_as_float(en.y);
                const float gb = __uint_as_float(en.z);
                float* orow = out + (size_t)en.x * D_ + colbase;
                #pragma unroll
                for (int j = 0; j < 4; ++j)
                    orow[j * 16] = ga * (accA[i][j][rr] + bkA[j])
                                 + gb * (accB[i][j][rr] + bkB[j]);
            }
        }
    }
}

// ---------------------------------------------------------------------------
// Launch
// ---------------------------------------------------------------------------
extern "C" void kernel_launch(void* const* d_in, const int* in_sizes, int n_in,
                              void* d_out, int out_size, void* d_ws, size_t ws_size,
                              hipStream_t stream) {
    const float* x   = (const float*)d_in[0];
    const float* eps = (const float*)d_in[1];
    const float* Wr  = (const float*)d_in[2];
    const float* br  = (const float*)d_in[3];
    const float* Wn  = (const float*)d_in[4];
    const float* bn  = (const float*)d_in[5];
    const float* Wk  = (const float*)d_in[6];
    const float* bk  = (const float*)d_in[7];
    float* out = (float*)d_out;

    // workspace layout (256B-aligned): ~28 MB total
    char* ws = (char*)d_ws;
    size_t off = 0;
    int* counts = (int*)(ws + off);                     off += 256;
    uint4* entries = (uint4*)(ws + off);                off += (size_t)NPAIR * CAP * 16;  // 7.3 MiB
    __hip_bfloat16* xb = (__hip_bfloat16*)(ws + off);   off += (size_t)NTOK * D_ * 2;     // 16 MiB
    __hip_bfloat16* wkt = (__hip_bfloat16*)(ws + off);  off += (size_t)E_ * D_ * D_ * 2;  // 4 MiB
    uint4* top2 = (uint4*)(ws + off);                   off += (size_t)NTOK * 16;         // 256 KiB
    int* wl = (int*)(ws + off);                         off += 1024;                      // worklist
    (void)ws_size;

    hipMemsetAsync(counts, 0, NPAIR * sizeof(int), stream);

    transpose_wk<<<dim3(16, 16, E_), dim3(32, 8), 0, stream>>>(Wk, wkt);
    router_kernel<<<dim3(NTOK / RV_TOK), dim3(RV_THR), 0, stream>>>(
        x, eps, Wr, br, Wn, bn, xb, top2);
    bucket_kernel<<<dim3(NTOK / 256), dim3(256), 0, stream>>>(top2, counts, entries);
    build_wl<<<dim3(1), dim3(64), 0, stream>>>(counts, wl);
    moe_gemm<<<dim3(WL_MAX * 4), dim3(256), 0, stream>>>(
        xb, wkt, bk, counts, entries, wl, out);
}

// Round 2
// 162.507 us; speedup vs baseline: 1.1567x; 1.1567x over previous
//
#include <hip/hip_runtime.h>
#include <hip/hip_bf16.h>
#include <math.h>

// Problem constants
#define B_    8
#define T_    2048
#define NTOK  (B_ * T_)   // 16384 tokens
#define D_    512
#define E_    8
#define NPAIR 28          // unordered expert pairs (top-2 always distinct)
#define CAP   NTOK        // per-pair bucket capacity (worst case)

// worklist: wl[0] = total mtiles; wl[1+i] = (pair<<8)|mtile.
// Sum ceil(cnt_p/128) <= 128 + 27 = 155 -> pad to 160 (multiple of 8 for XCD map)
#define WL_MAX 160

// router v6: 1024 blocks x 256 thr; 16 tok/block, 4 tok/wave.
#define RV_TOK    16
#define RV_THR    256
#define XS_STRIDE 132
#define WS_FLOATS 2108

typedef __attribute__((ext_vector_type(4))) float f32x4;
typedef __attribute__((ext_vector_type(8))) short short8;  // 8 bf16 (MFMA a/b frag)

__device__ __forceinline__ void async_load16(const void* g, void* l) {
    __builtin_amdgcn_global_load_lds(
        (const __attribute__((address_space(1))) unsigned int*)g,
        (__attribute__((address_space(3))) unsigned int*)l,
        16, 0, 0);
}

// ---------------------------------------------------------------------------
// Kernel 1: Wk[e][d][h] fp32 -> Wkt[e][h][d] bf16 (B^T layout for GEMM).
// ---------------------------------------------------------------------------
__global__ __launch_bounds__(256) void transpose_wk(
    const float* __restrict__ Wk, __hip_bfloat16* __restrict__ Wkt)
{
    __shared__ float tile[32][33];
    const int e  = blockIdx.z;
    const int d0 = blockIdx.x * 32;
    const int h0 = blockIdx.y * 32;
    const int tx = threadIdx.x, ty = threadIdx.y;

    const float* src = Wk + ((size_t)e * D_ + d0) * D_ + h0;
    #pragma unroll
    for (int r = ty; r < 32; r += 8)
        tile[r][tx] = src[(size_t)r * D_ + tx];
    __syncthreads();
    __hip_bfloat16* dst = Wkt + ((size_t)e * D_ + h0) * D_ + d0;
    #pragma unroll
    for (int r = ty; r < 32; r += 8)
        dst[(size_t)r * D_ + tx] = __float2bfloat16(tile[tx][r]);
}

// ---------------------------------------------------------------------------
// Kernel 2: router v6 (unchanged). x staged+bf16-converted once, W staged per
// 128-k chunk, fp32 fma, k-split lanes; 1024 blocks.
// ---------------------------------------------------------------------------
__global__ __launch_bounds__(RV_THR) void router_kernel(
    const float* __restrict__ x,     // [NTOK][D]
    const float* __restrict__ eps,   // [NTOK][E]
    const float* __restrict__ Wr,    // [D][E]
    const float* __restrict__ br,    // [E]
    const float* __restrict__ Wn,    // [D][E]
    const float* __restrict__ bn,    // [E]
    __hip_bfloat16* __restrict__ xb, // out: [NTOK][D] bf16
    uint4* __restrict__ top2)        // out: [NTOK] {i1|i2<<8, g1bits, g2bits}
{
    __shared__ float xs[RV_TOK * XS_STRIDE];  // 8.4 KB
    __shared__ float wsh[WS_FLOATS];          // 8.4 KB; row k at k*16+(k>>3)*4

    const int tid  = threadIdx.x;
    const int tok0 = blockIdx.x * RV_TOK;
    const int lane = tid & 63, wv = tid >> 6;
    const int kidx = lane >> 2, ts = lane & 3;
    const int tl = wv * 4 + ts;                // this lane's token
    const int wk = tid >> 1, wh = tid & 1;     // W stager: row, half

    float acc[16];  // [0..7]=x.Wr per expert, [8..15]=x.Wn
    #pragma unroll
    for (int c = 0; c < 16; ++c) acc[c] = 0.f;

    for (int kc = 0; kc < D_; kc += 128) {
        // stage x chunk [16 tok][128 k] + fused bf16 convert/store
        #pragma unroll
        for (int it = 0; it < 2; ++it) {
            const int f   = it * RV_THR + tid;      // f32x4 index in [0,512)
            const int row = f >> 5, col = (f & 31) * 4;
            const f32x4 v = *(const f32x4*)(x + (size_t)(tok0 + row) * D_ + kc + col);
            *(f32x4*)(xs + row * XS_STRIDE + col) = v;
            union { __hip_bfloat16 h[4]; uint2 u; } cv;
            cv.h[0] = __float2bfloat16(v.x); cv.h[1] = __float2bfloat16(v.y);
            cv.h[2] = __float2bfloat16(v.z); cv.h[3] = __float2bfloat16(v.w);
            *(uint2*)(xb + (size_t)(tok0 + row) * D_ + kc + col) = cv.u;
        }
        // stage W chunk [128 k][16 c] skewed; cols 0-7 = Wr, 8-15 = Wn
        {
            const float* src = (wh ? Wn : Wr) + (size_t)(kc + wk) * E_;
            const f32x4 w0 = *(const f32x4*)(src);
            const f32x4 w1 = *(const f32x4*)(src + 4);
            float* dst = wsh + wk * 16 + (wk >> 3) * 4 + wh * 8;
            *(f32x4*)(dst)     = w0;
            *(f32x4*)(dst + 4) = w1;
        }
        __syncthreads();

        // compute: this lane's 8 k-values of the chunk (k = kidx*8 + kk)
        const float* xra = xs + tl * XS_STRIDE + kidx * 8;
        const f32x4 xa0 = *(const f32x4*)(xra);
        const f32x4 xa1 = *(const f32x4*)(xra + 4);
        const float* wbase = wsh + kidx * 132;  // (kidx*8)*16 + kidx*4
        #pragma unroll
        for (int kk = 0; kk < 8; ++kk) {
            const float xav = (kk < 4) ? xa0[kk] : xa1[kk - 4];
            const float* wrow = wbase + kk * 16;
            #pragma unroll
            for (int c4 = 0; c4 < 4; ++c4) {
                const f32x4 w = *(const f32x4*)(wrow + c4 * 4);
                #pragma unroll
                for (int c = 0; c < 4; ++c)
                    acc[c4 * 4 + c] = fmaf(xav, w[c], acc[c4 * 4 + c]);
            }
        }
        __syncthreads();
    }

    // reduce across the 16 kidx lanes (stride 4): xor 4,8,16,32
    #pragma unroll
    for (int off = 4; off < 64; off <<= 1) {
        #pragma unroll
        for (int c = 0; c < 16; ++c)
            acc[c] += __shfl_xor(acc[c], off);
    }

    if (lane < 4) {  // kidx==0 lanes hold full dots for token tl
        const int tok = tok0 + tl;
        float nv[8];
        #pragma unroll
        for (int e = 0; e < 8; ++e) {
            const float nl = acc[8 + e] + bn[e];
            // jax.nn.softplus = max(z,0) + log1p(exp(-|z|))
            const float sp = fmaxf(nl, 0.f) + log1pf(expf(-fabsf(nl)));
            nv[e] = acc[e] + br[e] + eps[(size_t)tok * E_ + e] * sp;
        }
        // top-2, lax.top_k tie semantics (lowest index wins ties)
        int i1 = 0; float v1 = nv[0];
        #pragma unroll
        for (int e = 1; e < 8; ++e)
            if (nv[e] > v1) { v1 = nv[e]; i1 = e; }
        int i2 = -1; float v2 = -3.4e38f;
        #pragma unroll
        for (int e = 0; e < 8; ++e)
            if (e != i1 && nv[e] > v2) { v2 = nv[e]; i2 = e; }
        const float t  = expf(v2 - v1);
        const float g1 = 1.f / (1.f + t);
        const float g2 = t / (1.f + t);
        top2[tok] = make_uint4((unsigned)i1 | ((unsigned)i2 << 8),
                               __float_as_uint(g1), __float_as_uint(g2), 0u);
    }
}

// ---------------------------------------------------------------------------
// Kernel 3: PAIR bucket build (unchanged). Token -> one of 28 expert-pair
// buckets. LDS histogram -> 28 global atomics per block.
// ---------------------------------------------------------------------------
__global__ __launch_bounds__(256) void bucket_kernel(
    const uint4* __restrict__ top2,
    int* __restrict__ counts,     // [NPAIR] pre-zeroed
    uint4* __restrict__ entries)  // [NPAIR][CAP]
{
    __shared__ int hist[NPAIR];
    __shared__ int base[NPAIR];
    const int tid = threadIdx.x;
    const int tok = blockIdx.x * 256 + tid;
    if (tid < NPAIR) hist[tid] = 0;
    __syncthreads();
    const uint4 t = top2[tok];
    const int i1 = t.x & 0xff, i2 = (t.x >> 8) & 0xff;
    const int a = min(i1, i2), b = max(i1, i2);
    const unsigned ga = (i1 < i2) ? t.y : t.z;   // gate of expert a
    const unsigned gb = (i1 < i2) ? t.z : t.y;   // gate of expert b
    const int p = a * (15 - a) / 2 + (b - a - 1);
    const int l = atomicAdd(&hist[p], 1);
    __syncthreads();
    if (tid < NPAIR) base[tid] = atomicAdd(counts + tid, hist[tid]);
    __syncthreads();
    entries[(size_t)p * CAP + base[p] + l] = make_uint4((unsigned)tok, ga, gb, 0u);
}

// ---------------------------------------------------------------------------
// Kernel 3b: build worklist from final counts. 1 block, 1 wave.
// wl[0] = nm_total (<= 155); wl[1+i] = (p<<8)|mt.
// ---------------------------------------------------------------------------
__global__ __launch_bounds__(64) void build_wl(
    const int* __restrict__ counts, int* __restrict__ wl)
{
    const int t = threadIdx.x;  // 0..63, single wave
    const int nm = (t < NPAIR) ? ((counts[t] + 127) >> 7) : 0;
    int inc = nm;  // inclusive prefix sum across the wave
    #pragma unroll
    for (int d = 1; d < 64; d <<= 1) {
        const int v = __shfl_up(inc, d);
        if (t >= d) inc += v;
    }
    if (t == 63) wl[0] = inc;           // total mtiles
    const int ex = inc - nm;            // exclusive prefix
    for (int m = 0; m < nm; ++m)
        wl[1 + ex + m] = (t << 8) | m;
}

// ---------------------------------------------------------------------------
// Kernel 4: pair-grouped expert GEMM, DIRECT output.
//   R8 (this round) vs R7 post-mortem:
//   * REVERT k-major 16B-gather staging (it 4x'd L2 transactions; coalescing
//     beats LDS-conflict purity). Back to 64B-contiguous-per-row staging.
//   * Bank conflicts fixed the cheap way: XOR involution applied to BOTH the
//     per-lane global chunk select AND the ds_read slot (rule #21). For
//     f(row)=(row>>1)&3 the source-side select telescopes to a per-lane
//     constant: chunk = (lane&3)^((lane>>3)&3); read slot = quad^((lr>>1)&3).
//     LDS dest of global_load_lds stays linear. 16-lane read phase -> 2-way
//     bank aliasing = free (m136).
//   * T4 counted-vmcnt 3-buffer pipeline: 2 tiles always in flight,
//     s_waitcnt vmcnt(6) (never 0 mid-loop) + raw s_barrier; ONE barrier per
//     K-step; loads issued at iter t are consumed at iter t+2 (~2x320cyc of
//     MFMA hides the ~600-900cyc A-gather latency).
//   * T5 setprio(1) around the MFMA cluster (load/compute role-split exists).
//   * keep: worklist compact grid + XCD-aware id decode (FETCH 40->30MB).
// ---------------------------------------------------------------------------
__global__ __launch_bounds__(256, 2) void moe_gemm(
    const __hip_bfloat16* __restrict__ xb,   // [NTOK][D] bf16
    const __hip_bfloat16* __restrict__ wkt,  // [E][D(out)][D(in)] bf16 (B^T)
    const float* __restrict__ bk,            // [E][D]
    const int* __restrict__ counts,          // [NPAIR]
    const uint4* __restrict__ entries,       // [NPAIR][CAP]
    const int* __restrict__ wl,              // [1+WL_MAX]
    float* __restrict__ out)                 // [NTOK][D] fp32 (fully written)
{
    constexpr int BM = 128, BN = 128, BK = 32;
    constexpr int NT = D_ / BK;  // 16 K-steps
    // row-major [row][BK] tiles; slot s of row r holds global chunk s^f(r),
    // f(r) = (r>>1)&3  (involution via XOR)
    __shared__ __hip_bfloat16 As[3][BM * BK];       // 3 x 8 KB
    __shared__ __hip_bfloat16 Bs[3][2][BN * BK];    // 3 x 16 KB
    __shared__ uint4 ent[BM];                       // 2 KB   (total 74 KB)

    // id = g*32 + nt*8 + j ; mtile = g*8 + j ; XCD = id%8 = j for all 4 nt
    const int id = blockIdx.x;
    const int g = id >> 5, r = id & 31;
    const int nt = r >> 3;
    const int mi = g * 8 + (r & 7);
    const int nmtot = wl[0];
    if (mi >= nmtot) return;
    const int we = wl[1 + mi];
    const int p = we >> 8, mt = we & 255;
    const int cnt = counts[p];

    // decode pair p -> (e1 < e2)
    int e1 = 0, rem = p;
    while (rem >= 7 - e1) { rem -= 7 - e1; ++e1; }
    const int e2 = e1 + 1 + rem;

    const int tid = threadIdx.x;
    const int wave = tid >> 6, lane = tid & 63;

    if (tid < BM) {
        const int idx = mt * BM + tid;
        ent[tid] = (idx < cnt) ? entries[(size_t)p * CAP + idx]
                               : make_uint4(0u, 0u, 0u, 0u);
    }
    __syncthreads();

    const int quad = lane >> 4, lr = lane & 15;
    const int wm = wave >> 1, wn = wave & 1;

    // --- staging geometry (64B contiguous per row, 16 rows per wave-call) ---
    // lane -> (row16 = lane>>2, chunk c = (lane&3) ^ f(row)); f telescopes to
    // (lane>>3)&3 because row = wave*32 + (lane>>2) and wave*32>>1 is mult of 16.
    const int r16 = lane >> 2;
    const int csel = (lane & 3) ^ ((lane >> 3) & 3);   // swizzled 16B chunk
    const int rA0 = wave * 32 + r16;                   // rows [w*32, w*32+16)
    const size_t tA0 = ent[rA0].x;
    const size_t tA1 = ent[rA0 + 16].x;
    const __hip_bfloat16* gA0 = xb + tA0 * D_ + csel * 8;
    const __hip_bfloat16* gA1 = xb + tA1 * D_ + csel * 8;
    const __hip_bfloat16* gB1 = wkt + ((size_t)e1 * D_ + nt * BN + rA0) * D_ + csel * 8;
    const __hip_bfloat16* gB2 = wkt + ((size_t)e2 * D_ + nt * BN + rA0) * D_ + csel * 8;

    // read-side swizzled slot (per-lane constant): quad ^ ((lr>>1)&3)
    const int so = (quad ^ ((lr >> 1) & 3)) * 8;

    f32x4 accA[4][4], accB[4][4];
    #pragma unroll
    for (int i = 0; i < 4; ++i)
        #pragma unroll
        for (int j = 0; j < 4; ++j) {
            accA[i][j] = (f32x4){0.f, 0.f, 0.f, 0.f};
            accB[i][j] = (f32x4){0.f, 0.f, 0.f, 0.f};
        }

    // 6 async loads per wave per STAGE -> vmcnt counts in units of 6
#define STAGE(buf, k0) do {                                        \
        __hip_bfloat16* aB  = &As[buf][wave * 1024];               \
        __hip_bfloat16* b1B = &Bs[buf][0][wave * 1024];            \
        __hip_bfloat16* b2B = &Bs[buf][1][wave * 1024];            \
        async_load16(gA0 + (k0), aB);                              \
        async_load16(gA1 + (k0), aB + 512);                        \
        async_load16(gB1 + (k0), b1B);                             \
        async_load16(gB1 + 16 * D_ + (k0), b1B + 512);             \
        async_load16(gB2 + (k0), b2B);                             \
        async_load16(gB2 + 16 * D_ + (k0), b2B + 512);             \
    } while (0)

#define COMPUTE(buf) do {                                                      \
        short8 a[4], b1v[4], b2v[4];                                           \
        _Pragma("unroll")                                                      \
        for (int i = 0; i < 4; ++i)                                            \
            a[i] = *(const short8*)(&As[buf][(wm * 64 + i * 16 + lr) * 32 + so]); \
        _Pragma("unroll")                                                      \
        for (int j = 0; j < 4; ++j) {                                          \
            b1v[j] = *(const short8*)(&Bs[buf][0][(wn * 64 + j * 16 + lr) * 32 + so]); \
            b2v[j] = *(const short8*)(&Bs[buf][1][(wn * 64 + j * 16 + lr) * 32 + so]); \
        }                                                                      \
        __builtin_amdgcn_s_setprio(1);                                         \
        _Pragma("unroll")                                                      \
        for (int i = 0; i < 4; ++i)                                            \
            _Pragma("unroll")                                                  \
            for (int j = 0; j < 4; ++j) {                                      \
                accA[i][j] = __builtin_amdgcn_mfma_f32_16x16x32_bf16(          \
                    a[i], b1v[j], accA[i][j], 0, 0, 0);                        \
                accB[i][j] = __builtin_amdgcn_mfma_f32_16x16x32_bf16(          \
                    a[i], b2v[j], accB[i][j], 0, 0, 0);                        \
            }                                                                  \
        __builtin_amdgcn_s_setprio(0);                                         \
    } while (0)

    // prologue: tiles 0 and 1 in flight (12 outstanding VMEM ops per wave)
    STAGE(0, 0);
    STAGE(1, BK);

    // steady state: wait oldest 6 (tile t done; tile t+1 stays in flight),
    // barrier, refill (tile t+2 into the buffer freed at iter t-1), compute.
    #pragma unroll
    for (int t = 0; t < NT - 1; ++t) {
        asm volatile("s_waitcnt vmcnt(6)" ::: "memory");
        __builtin_amdgcn_s_barrier();
        if (t + 2 < NT) STAGE((t + 2) % 3, (t + 2) * BK);
        COMPUTE(t % 3);
    }
    asm volatile("s_waitcnt vmcnt(0)" ::: "memory");
    __builtin_amdgcn_s_barrier();
    COMPUTE((NT - 1) % 3);

#undef STAGE
#undef COMPUTE

    const int colbase = nt * BN + wn * 64 + lr;
    float bkA[4], bkB[4];
    #pragma unroll
    for (int j = 0; j < 4; ++j) {
        bkA[j] = bk[e1 * D_ + colbase + j * 16];
        bkB[j] = bk[e2 * D_ + colbase + j * 16];
    }

    #pragma unroll
    for (int i = 0; i < 4; ++i) {
        #pragma unroll
        for (int rr = 0; rr < 4; ++rr) {
            const int row = wm * 64 + i * 16 + quad * 4 + rr;  // C: row = quad*4+reg
            if (mt * BM + row < cnt) {
                const uint4 en = ent[row];
                const float ga = __uint_as_float(en.y);
                const float gb = __uint_as_float(en.z);
                float* orow = out + (size_t)en.x * D_ + colbase;
                #pragma unroll
                for (int j = 0; j < 4; ++j)
                    orow[j * 16] = ga * (accA[i][j][rr] + bkA[j])
                                 + gb * (accB[i][j][rr] + bkB[j]);
            }
        }
    }
}

// ---------------------------------------------------------------------------
// Launch
// ---------------------------------------------------------------------------
extern "C" void kernel_launch(void* const* d_in, const int* in_sizes, int n_in,
                              void* d_out, int out_size, void* d_ws, size_t ws_size,
                              hipStream_t stream) {
    const float* x   = (const float*)d_in[0];
    const float* eps = (const float*)d_in[1];
    const float* Wr  = (const float*)d_in[2];
    const float* br  = (const float*)d_in[3];
    const float* Wn  = (const float*)d_in[4];
    const float* bn  = (const float*)d_in[5];
    const float* Wk  = (const float*)d_in[6];
    const float* bk  = (const float*)d_in[7];
    float* out = (float*)d_out;

    // workspace layout (256B-aligned): ~28 MB total
    char* ws = (char*)d_ws;
    size_t off = 0;
    int* counts = (int*)(ws + off);                     off += 256;
    uint4* entries = (uint4*)(ws + off);                off += (size_t)NPAIR * CAP * 16;  // 7.3 MiB
    __hip_bfloat16* xb = (__hip_bfloat16*)(ws + off);   off += (size_t)NTOK * D_ * 2;     // 16 MiB
    __hip_bfloat16* wkt = (__hip_bfloat16*)(ws + off);  off += (size_t)E_ * D_ * D_ * 2;  // 4 MiB
    uint4* top2 = (uint4*)(ws + off);                   off += (size_t)NTOK * 16;         // 256 KiB
    int* wl = (int*)(ws + off);                         off += 1024;                      // worklist
    (void)ws_size;

    hipMemsetAsync(counts, 0, NPAIR * sizeof(int), stream);

    transpose_wk<<<dim3(16, 16, E_), dim3(32, 8), 0, stream>>>(Wk, wkt);
    router_kernel<<<dim3(NTOK / RV_TOK), dim3(RV_THR), 0, stream>>>(
        x, eps, Wr, br, Wn, bn, xb, top2);
    bucket_kernel<<<dim3(NTOK / 256), dim3(256), 0, stream>>>(top2, counts, entries);
    build_wl<<<dim3(1), dim3(64), 0, stream>>>(counts, wl);
    moe_gemm<<<dim3(WL_MAX * 4), dim3(256), 0, stream>>>(
        xb, wkt, bk, counts, entries, wl, out);
}